// Round 10
// baseline (267.350 us; speedup 1.0000x reference)
//
#include <hip/hip_runtime.h>
#include <hip/hip_cooperative_groups.h>
#include <math.h>

namespace cg = cooperative_groups;

#define VNUM 50000
#define OUTF 128
#define NEDGE 1600000
#define EPSF 1e-7f

#define CONV_BLOCKS 6250    // 50000*128 / (256*4)
#define BFRAG_BLOCKS 64     // 16384 uint pairs / 256

#define CHUNK 2048          // edges per coarse block
#define NCB 49              // coarse bins: tidx>>10 (1024 vertices/bin)
#define COARSE_BLOCKS 782   // ceil(NEDGE/CHUNK)
#define BSTRIDE 36864       // fixed coarse8 segment stride; mean 32768 + 23 sigma
#define NSUB 4              // sub-blocks per bin (R8: 8 regressed +6.5us; 4 proven)
#define FINE_BLOCKS (NCB * NSUB)   // 196
#define RPT 9               // records/thread in fused sort: 9*1024 >= 36864/4

typedef __attribute__((ext_vector_type(8))) short short8;
typedef __attribute__((ext_vector_type(4))) float v4f;

// ---------------------------------------------------------------------------
// bf16 helpers (RNE)
// ---------------------------------------------------------------------------
__device__ __forceinline__ unsigned short f2bf(float f) {
    union { float f; unsigned int u; } c; c.f = f;
    unsigned int u = c.u;
    return (unsigned short)((u + 0x7FFFu + ((u >> 16) & 1u)) >> 16);
}
__device__ __forceinline__ float bf16_lo(unsigned int p) {
    union { unsigned int u; float f; } c; c.u = p << 16; return c.f;
}
__device__ __forceinline__ float bf16_hi(unsigned int p) {
    union { unsigned int u; float f; } c; c.u = p & 0xFFFF0000u; return c.f;
}

__device__ __forceinline__ int wave_incl_scan(int v, int lane) {
#pragma unroll
    for (int off = 1; off < 64; off <<= 1) {
        const int o = __shfl_up(v, off, 64);
        if (lane >= off) v += o;
    }
    return v;
}

// ---------------------------------------------------------------------------
// prep: (a) vrepr f32 -> packed bf16x2, (b) ccursor init (fixed-stride bins)
// + offs[VNUM]=NEDGE (constant), (c) MFMA B-fragment build.
// ---------------------------------------------------------------------------
__global__ __launch_bounds__(256) void prep_kernel(
    const float* __restrict__ vrepr, unsigned int* __restrict__ vrepr16,
    int* __restrict__ ccursor, int* __restrict__ offs,
    const float* __restrict__ loc_w, const float* __restrict__ std_w,
    unsigned int* bfrag)
{
    const int b = blockIdx.x, tid = threadIdx.x;
    if (b < CONV_BLOCKS) {
        const size_t base = (size_t)b * 1024 + tid * 4;
        const float4 v = *reinterpret_cast<const float4*>(vrepr + base);
        uint2 o;
        o.x = (unsigned)f2bf(v.x) | ((unsigned)f2bf(v.y) << 16);
        o.y = (unsigned)f2bf(v.z) | ((unsigned)f2bf(v.w) << 16);
        *reinterpret_cast<uint2*>(vrepr16 + base / 2) = o;
    } else if (b == CONV_BLOCKS) {
        if (tid < NCB) ccursor[tid] = tid * BSTRIDE;
        if (tid == 63) offs[VNUM] = NEDGE;
    } else {
        const int p = (b - (CONV_BLOCKS + 1)) * 256 + tid; // 0..16383
        const int j2 = p & 3, lq = (p >> 2) & 63, ks = (p >> 8) & 3, ct = p >> 10;
        const int k = ks * 32 + (lq >> 4) * 8 + j2 * 2;
        const int n = ct * 16 + (lq & 15);
        const float* wsrc = (n >> 7) ? std_w : loc_w;
        const int c = n & 127;
        bfrag[p] = (unsigned)f2bf(wsrc[c * 128 + k]) |
                   ((unsigned)f2bf(wsrc[c * 128 + k + 1]) << 16);
    }
}

// ---------------------------------------------------------------------------
// coarse: partition edges into 49 fixed-stride bin segments via LDS staging
// + bulk-reserved contiguous runs. rec = { sidx<<16 | bf16(w), tidx }
// R9: NT loads on the 4 edge streams (read-once; keeps L2 for coarse8).
// ---------------------------------------------------------------------------
__global__ __launch_bounds__(256) void coarse_kernel(
    const int* __restrict__ sidx, const int* __restrict__ tidx,
    const float* __restrict__ enorm, const float* __restrict__ esgn,
    int* __restrict__ ccursor, uint2* __restrict__ coarse8)
{
    __shared__ uint2 lrec[CHUNK];      // 16 KB
    __shared__ int lcnt[4][NCB];
    __shared__ int lbase[4][NCB];
    __shared__ int loffs[NCB];
    __shared__ int grun[NCB];

    const int tid = threadIdx.x, lane = tid & 63, wv = tid >> 6;
    const int base = blockIdx.x * CHUNK;
    const int n = min(CHUNK, NEDGE - base);

    for (int i = tid; i < 4 * NCB; i += 256) (&lcnt[0][0])[i] = 0;
    __syncthreads();

    uint2 rec[8];
#pragma unroll
    for (int j = 0; j < 8; ++j) {
        const int e = base + j * 256 + tid;
        if (e < NEDGE) {
            const int t = __builtin_nontemporal_load(tidx + e);
            const float w = __builtin_nontemporal_load(esgn + e) *
                            __builtin_nontemporal_load(enorm + e);
            rec[j].x = ((unsigned)__builtin_nontemporal_load(sidx + e) << 16) |
                       (unsigned)f2bf(w);
            rec[j].y = (unsigned)t;
            atomicAdd(&lcnt[wv][t >> 10], 1);
        }
    }
    __syncthreads();

    if (tid < 64) {
        int c0 = 0, c1 = 0, c2 = 0, c3 = 0, tot = 0;
        if (lane < NCB) {
            c0 = lcnt[0][lane]; c1 = lcnt[1][lane];
            c2 = lcnt[2][lane]; c3 = lcnt[3][lane];
            tot = c0 + c1 + c2 + c3;
        }
        const int inc = wave_incl_scan(tot, lane);
        const int ex = inc - tot;
        if (lane < NCB) {
            loffs[lane]    = ex;
            lbase[0][lane] = ex;
            lbase[1][lane] = ex + c0;
            lbase[2][lane] = ex + c0 + c1;
            lbase[3][lane] = ex + c0 + c1 + c2;
            grun[lane] = atomicAdd(&ccursor[lane], tot);
        }
    }
    __syncthreads();

#pragma unroll
    for (int j = 0; j < 8; ++j) {
        const int e = base + j * 256 + tid;
        if (e < NEDGE) {
            const int cb = (int)(rec[j].y >> 10);
            const int pos = atomicAdd(&lbase[wv][cb], 1);
            lrec[pos] = rec[j];
        }
    }
    __syncthreads();

    for (int i = tid; i < n; i += 256) {
        const uint2 r = lrec[i];
        const int cb = (int)(r.y >> 10);
        coarse8[grun[cb] + (i - loffs[cb])] = r;
    }
}

// ---------------------------------------------------------------------------
// sort_fine (R9, cooperative): fused hist + scatter. Each sub-block loads
// its <=9216-record segment into REGISTERS (one coarse8 read total, NT),
// builds LDS hist, stores its hcnt slice, grid.sync(), then computes bases
// from the NSUB slices + ccursor prefix and scatters from registers.
// Replaces hist_kernel + scatter_fine_kernel (-12.8MB traffic, -1 launch).
// ---------------------------------------------------------------------------
__global__ __launch_bounds__(1024) void sort_fine_kernel(
    const uint2* __restrict__ coarse8, const int* __restrict__ ccursor,
    int* __restrict__ hcnt, int* __restrict__ offs,
    unsigned int* __restrict__ pairs)
{
    __shared__ int cell[1024];   // hist, then cursors
    __shared__ int wsum[16];
    __shared__ int sh_s0;
    const int tid = threadIdx.x, lane = tid & 63, wv = tid >> 6;
    const int bin = blockIdx.x >> 2, s = blockIdx.x & 3;
    const int bs = bin * BSTRIDE;

    // packed exclusive prefix of bin lengths (wave 0)
    if (tid < 64) {
        const int lenl = (tid < NCB) ? (ccursor[tid] - tid * BSTRIDE) : 0;
        const int incc = wave_incl_scan(lenl, tid);
        if (tid == bin) sh_s0 = incc - lenl;
    }

    const int len = ccursor[bin] - bs;
    const int qs = bs + ((len * s) >> 2);
    const int qe = bs + ((len * (s + 1)) >> 2);

    cell[tid] = 0;
    __syncthreads();

    uint2 rec[RPT];
#pragma unroll
    for (int j = 0; j < RPT; ++j) {
        const int idx = qs + j * 1024 + tid;
        if (idx < qe) {
            const uint2 r = { __builtin_nontemporal_load(&coarse8[idx].x),
                              __builtin_nontemporal_load(&coarse8[idx].y) };
            rec[j] = r;
            atomicAdd(&cell[r.y & 1023], 1);
        }
    }
    __syncthreads();
    hcnt[blockIdx.x * 1024 + tid] = cell[tid];

    cg::this_grid().sync();

    int c[NSUB];
    int tot = 0, pre = 0;
#pragma unroll
    for (int j = 0; j < NSUB; ++j) {
        c[j] = hcnt[(bin * NSUB + j) * 1024 + tid];
        tot += c[j];
        if (j < s) pre += c[j];
    }

    const int inc = wave_incl_scan(tot, lane);
    if (lane == 63) wsum[wv] = inc;
    __syncthreads();
    if (tid == 0) {
        int run = 0;
        for (int i = 0; i < 16; ++i) { const int t = wsum[i]; wsum[i] = run; run += t; }
    }
    __syncthreads();
    const int ex = sh_s0 + wsum[wv] + inc - tot;   // global offs for vertex gv
    const int gv = (bin << 10) + tid;
    if (s == 0 && gv < VNUM) offs[gv] = ex;
    cell[tid] = ex + pre;
    __syncthreads();

#pragma unroll
    for (int j = 0; j < RPT; ++j) {
        const int idx = qs + j * 1024 + tid;
        if (idx < qe) {
            const int pos = atomicAdd(&cell[rec[j].y & 1023], 1);
            pairs[pos] = rec[j].x;
        }
    }
}

// ---------------------------------------------------------------------------
// aggregate: one wave per vertex, lane covers cols (2l, 2l+1). 256 B
// coalesced bf16-row gathers, unroll-12, CACHED pairs loads (R8-proven) +
// nontemporal PACKED-BF16 store (WRITE 25->12.5MB). Same rounding point as
// gemm's old pack -> bit-identical output.
// ---------------------------------------------------------------------------
__global__ __launch_bounds__(256) void aggregate_kernel(
    const int* __restrict__ offs, const unsigned int* __restrict__ pairs,
    const unsigned int* __restrict__ vrepr16, unsigned int* __restrict__ accu)
{
    const int v = blockIdx.x * 4 + (threadIdx.x >> 6);
    const int l = threadIdx.x & 63;
    int i = offs[v];
    const int end = offs[v + 1];

    float a0 = 0.0f, a1 = 0.0f;
    for (; i + 12 <= end; i += 12) {
        unsigned p[12], r[12];
#pragma unroll
        for (int j = 0; j < 12; ++j) p[j] = pairs[i + j];
#pragma unroll
        for (int j = 0; j < 12; ++j) r[j] = vrepr16[(size_t)(p[j] >> 16) * 64 + l];
#pragma unroll
        for (int j = 0; j < 12; ++j) {
            const float w = bf16_lo(p[j]);
            a0 = fmaf(bf16_lo(r[j]), w, a0);
            a1 = fmaf(bf16_hi(r[j]), w, a1);
        }
    }
    for (; i + 4 <= end; i += 4) {
        unsigned p[4], r[4];
#pragma unroll
        for (int j = 0; j < 4; ++j) p[j] = pairs[i + j];
#pragma unroll
        for (int j = 0; j < 4; ++j) r[j] = vrepr16[(size_t)(p[j] >> 16) * 64 + l];
#pragma unroll
        for (int j = 0; j < 4; ++j) {
            const float w = bf16_lo(p[j]);
            a0 = fmaf(bf16_lo(r[j]), w, a0);
            a1 = fmaf(bf16_hi(r[j]), w, a1);
        }
    }
    for (; i < end; ++i) {
        const unsigned p = pairs[i];
        const unsigned r = vrepr16[(size_t)(p >> 16) * 64 + l];
        const float w = bf16_lo(p);
        a0 = fmaf(bf16_lo(r), w, a0); a1 = fmaf(bf16_hi(r), w, a1);
    }
    const unsigned pk = (unsigned)f2bf(a0) | ((unsigned)f2bf(a1) << 16);
    __builtin_nontemporal_store(pk, accu + (size_t)v * 128 + l);
}

// ---------------------------------------------------------------------------
// gemm via MFMA 16x16x32 bf16. A-tile read pre-packed bf16: 256 B/row,
// no f32->bf16 pack phase. In-place safe: block reads exactly the acc16
// region of the rows it overwrites.
// ---------------------------------------------------------------------------
__global__ __launch_bounds__(256) void gemm_mfma_kernel(
    const unsigned int* accu, const unsigned int* __restrict__ bfrag,
    const float* __restrict__ loc_b, const float* __restrict__ std_b,
    float* out)
{
    __shared__ unsigned short tile[16][136];   // bf16, padded
    const int t = threadIdx.x;
    const int row0 = blockIdx.x * 16;
    const int l = t & 63, w = t >> 6;

    short8 bfr[4][4];
#pragma unroll
    for (int ct = 0; ct < 4; ++ct)
#pragma unroll
        for (int ks = 0; ks < 4; ++ks)
            bfr[ct][ks] = *reinterpret_cast<const short8*>(
                bfrag + ((((w * 4 + ct) * 4 + ks) * 64 + l) << 2));

    {
        const uint4 av = *reinterpret_cast<const uint4*>(
            accu + (size_t)(row0 + (t >> 4)) * 128 + (t & 15) * 4);
        *reinterpret_cast<uint4*>(&tile[t >> 4][(t & 15) * 8]) = av;
    }
    __syncthreads();

    const int m = l & 15, q = l >> 4;
    v4f accv[4];
#pragma unroll
    for (int ct = 0; ct < 4; ++ct) accv[ct] = (v4f){0.0f, 0.0f, 0.0f, 0.0f};

#pragma unroll
    for (int ks = 0; ks < 4; ++ks) {
        const short8 a = *reinterpret_cast<const short8*>(&tile[m][ks * 32 + q * 8]);
#pragma unroll
        for (int ct = 0; ct < 4; ++ct)
            accv[ct] = __builtin_amdgcn_mfma_f32_16x16x32_bf16(
                a, bfr[ct][ks], accv[ct], 0, 0, 0);
    }

#pragma unroll
    for (int ct = 0; ct < 4; ++ct) {
        const int colg = (w * 4 + ct) * 16 + m;
        const int h = colg >> 7, c = colg & 127;
        const float bias = (h ? std_b : loc_b)[c];
        float* dst = out + (h ? (size_t)VNUM * OUTF : (size_t)0);
#pragma unroll
        for (int reg = 0; reg < 4; ++reg) {
            const int row = row0 + q * 4 + reg;
            float x = accv[ct][reg] + bias;
            if (h) x = fmaxf(x, 0.0f) + log1pf(expf(-fabsf(x))) + EPSF;
            dst[(size_t)row * OUTF + c] = x;
        }
    }
}

// Fallback gemm (no workspace): f32 vector path, unpacks bf16 acc.
__global__ __launch_bounds__(256) void gemm_fallback_kernel(
    const unsigned int* accu,
    const float* __restrict__ loc_w, const float* __restrict__ loc_b,
    const float* __restrict__ std_w, const float* __restrict__ std_b,
    float* out)
{
    __shared__ float tile[16][OUTF];
    const int t = threadIdx.x;
    const int row0 = blockIdx.x * 16;
    {
        const uint4 av = *reinterpret_cast<const uint4*>(
            accu + (size_t)(row0 + (t >> 4)) * 128 + (t & 15) * 4);
        float* dst = &tile[t >> 4][(t & 15) * 8];
        dst[0] = bf16_lo(av.x); dst[1] = bf16_hi(av.x);
        dst[2] = bf16_lo(av.y); dst[3] = bf16_hi(av.y);
        dst[4] = bf16_lo(av.z); dst[5] = bf16_hi(av.z);
        dst[6] = bf16_lo(av.w); dst[7] = bf16_hi(av.w);
    }
    __syncthreads();
    const int is_std = t >> 7;
    const int c = t & 127;
    const float* w = (is_std ? std_w : loc_w) + (size_t)c * OUTF;
    const float bias = is_std ? std_b[c] : loc_b[c];
    float accv[16];
#pragma unroll
    for (int r = 0; r < 16; ++r) accv[r] = 0.0f;
    for (int k = 0; k < OUTF; k += 4) {
        const float4 wv = *reinterpret_cast<const float4*>(w + k);
#pragma unroll
        for (int r = 0; r < 16; ++r) {
            const float4 pv = *reinterpret_cast<const float4*>(&tile[r][k]);
            float a = accv[r];
            a = fmaf(pv.x, wv.x, a); a = fmaf(pv.y, wv.y, a);
            a = fmaf(pv.z, wv.z, a); a = fmaf(pv.w, wv.w, a);
            accv[r] = a;
        }
    }
    float* dst_base = out + (is_std ? (size_t)VNUM * OUTF : (size_t)0);
#pragma unroll
    for (int r = 0; r < 16; ++r) {
        const float x = accv[r] + bias;
        dst_base[(size_t)(row0 + r) * OUTF + c] =
            is_std ? (fmaxf(x, 0.0f) + log1pf(expf(-fabsf(x))) + EPSF) : x;
    }
}

extern "C" void kernel_launch(void* const* d_in, const int* in_sizes, int n_in,
                              void* d_out, int out_size, void* d_ws, size_t ws_size,
                              hipStream_t stream) {
    const int*   sidx  = (const int*)  d_in[0];
    const int*   tidx  = (const int*)  d_in[1];
    const float* enorm = (const float*)d_in[2];
    const float* esgn  = (const float*)d_in[3];
    const float* vrepr = (const float*)d_in[4];
    const float* loc_w = (const float*)d_in[5];
    const float* loc_b = (const float*)d_in[6];
    const float* std_w = (const float*)d_in[7];
    const float* std_b = (const float*)d_in[8];

    float* out = (float*)d_out;

    // coarse8: 49 fixed-stride segments (49*36864*8B = 14.45 MB) in the loc
    // half of out (25.6 MB); dead after sort_fine. Then the loc half holds
    // acc16 (packed bf16, identity-strided: row v -> uints [v*128, v*128+64)).
    uint2* coarse8 = (uint2*)out;
    unsigned int* accu = (unsigned int*)out;

    // std-half scratch layout (~5.05M of 6.4M words):
    //   pairs 1.6M | vrepr16 3.2M | offs 50001 | ccursor 49 | hcnt 196*1024
    unsigned int* sbase   = (unsigned int*)(out + (size_t)VNUM * OUTF);
    unsigned int* pairs   = sbase;
    unsigned int* vrepr16 = sbase + NEDGE;
    int* offs    = (int*)(sbase + NEDGE + (size_t)VNUM * 64);
    int* ccursor = offs + VNUM + 1;
    int* hcnt    = ccursor + NCB;

    const bool use_ws = ws_size >= 16384 * sizeof(unsigned int);  // 64 KB
    unsigned int* bfrag = use_ws ? (unsigned int*)d_ws : nullptr;

    const int prep_blocks = CONV_BLOCKS + 1 + (use_ws ? BFRAG_BLOCKS : 0);
    prep_kernel  <<<prep_blocks, 256, 0, stream>>>(vrepr, vrepr16, ccursor,
                                                   offs, loc_w, std_w, bfrag);
    coarse_kernel<<<COARSE_BLOCKS, 256, 0, stream>>>(sidx, tidx, enorm, esgn,
                                                     ccursor, coarse8);

    {
        const uint2* c8 = coarse8;
        const int* cc = ccursor;
        void* args[] = { (void*)&c8, (void*)&cc, (void*)&hcnt,
                         (void*)&offs, (void*)&pairs };
        hipLaunchCooperativeKernel((const void*)sort_fine_kernel,
                                   dim3(FINE_BLOCKS), dim3(1024),
                                   args, 0, stream);
    }

    aggregate_kernel<<<VNUM / 4, 256, 0, stream>>>(offs, pairs, vrepr16, accu);

    if (use_ws) {
        gemm_mfma_kernel<<<VNUM / 16, 256, 0, stream>>>(accu, bfrag, loc_b, std_b, out);
    } else {
        gemm_fallback_kernel<<<VNUM / 16, 256, 0, stream>>>(accu, loc_w, loc_b,
                                                            std_w, std_b, out);
    }
}

// Round 11
// 227.930 us; speedup vs baseline: 1.1729x; 1.1729x over previous
//
#include <hip/hip_runtime.h>
#include <math.h>

#define VNUM 50000
#define OUTF 128
#define NEDGE 1600000
#define EPSF 1e-7f

#define CONV_BLOCKS 6250    // 50000*128 / (256*4)
#define BFRAG_BLOCKS 64     // 16384 uint pairs / 256

#define CHUNK 2048          // edges per coarse block
#define NCB 49              // coarse bins: tidx>>10 (1024 vertices/bin)
#define COARSE_BLOCKS 782   // ceil(NEDGE/CHUNK)
#define BSTRIDE 36864       // fixed coarse8 segment stride; mean 32768 + 23 sigma
#define NSUB 4              // sub-blocks per bin (R8: 8 = +6.5us; R10: coop fuse = +35us)
#define FINE_BLOCKS (NCB * NSUB)   // 196

typedef __attribute__((ext_vector_type(8))) short short8;
typedef __attribute__((ext_vector_type(4))) float v4f;

// ---------------------------------------------------------------------------
// bf16 helpers (RNE)
// ---------------------------------------------------------------------------
__device__ __forceinline__ unsigned short f2bf(float f) {
    union { float f; unsigned int u; } c; c.f = f;
    unsigned int u = c.u;
    return (unsigned short)((u + 0x7FFFu + ((u >> 16) & 1u)) >> 16);
}
__device__ __forceinline__ float bf16_lo(unsigned int p) {
    union { unsigned int u; float f; } c; c.u = p << 16; return c.f;
}
__device__ __forceinline__ float bf16_hi(unsigned int p) {
    union { unsigned int u; float f; } c; c.u = p & 0xFFFF0000u; return c.f;
}

__device__ __forceinline__ int wave_incl_scan(int v, int lane) {
#pragma unroll
    for (int off = 1; off < 64; off <<= 1) {
        const int o = __shfl_up(v, off, 64);
        if (lane >= off) v += o;
    }
    return v;
}

// ---------------------------------------------------------------------------
// prep: (a) vrepr f32 -> packed bf16x2, (b) ccursor init (fixed-stride bins)
// + offs[VNUM]=NEDGE (constant), (c) MFMA B-fragment build.
// ---------------------------------------------------------------------------
__global__ __launch_bounds__(256) void prep_kernel(
    const float* __restrict__ vrepr, unsigned int* __restrict__ vrepr16,
    int* __restrict__ ccursor, int* __restrict__ offs,
    const float* __restrict__ loc_w, const float* __restrict__ std_w,
    unsigned int* bfrag)
{
    const int b = blockIdx.x, tid = threadIdx.x;
    if (b < CONV_BLOCKS) {
        const size_t base = (size_t)b * 1024 + tid * 4;
        const float4 v = *reinterpret_cast<const float4*>(vrepr + base);
        uint2 o;
        o.x = (unsigned)f2bf(v.x) | ((unsigned)f2bf(v.y) << 16);
        o.y = (unsigned)f2bf(v.z) | ((unsigned)f2bf(v.w) << 16);
        *reinterpret_cast<uint2*>(vrepr16 + base / 2) = o;
    } else if (b == CONV_BLOCKS) {
        if (tid < NCB) ccursor[tid] = tid * BSTRIDE;
        if (tid == 63) offs[VNUM] = NEDGE;
    } else {
        const int p = (b - (CONV_BLOCKS + 1)) * 256 + tid; // 0..16383
        const int j2 = p & 3, lq = (p >> 2) & 63, ks = (p >> 8) & 3, ct = p >> 10;
        const int k = ks * 32 + (lq >> 4) * 8 + j2 * 2;
        const int n = ct * 16 + (lq & 15);
        const float* wsrc = (n >> 7) ? std_w : loc_w;
        const int c = n & 127;
        bfrag[p] = (unsigned)f2bf(wsrc[c * 128 + k]) |
                   ((unsigned)f2bf(wsrc[c * 128 + k + 1]) << 16);
    }
}

// ---------------------------------------------------------------------------
// coarse: partition edges into 49 fixed-stride bin segments via LDS staging
// + bulk-reserved contiguous runs. rec = { sidx<<16 | bf16(w), tidx }
// ---------------------------------------------------------------------------
__global__ __launch_bounds__(256) void coarse_kernel(
    const int* __restrict__ sidx, const int* __restrict__ tidx,
    const float* __restrict__ enorm, const float* __restrict__ esgn,
    int* __restrict__ ccursor, uint2* __restrict__ coarse8)
{
    __shared__ uint2 lrec[CHUNK];      // 16 KB
    __shared__ int lcnt[4][NCB];
    __shared__ int lbase[4][NCB];
    __shared__ int loffs[NCB];
    __shared__ int grun[NCB];

    const int tid = threadIdx.x, lane = tid & 63, wv = tid >> 6;
    const int base = blockIdx.x * CHUNK;
    const int n = min(CHUNK, NEDGE - base);

    for (int i = tid; i < 4 * NCB; i += 256) (&lcnt[0][0])[i] = 0;
    __syncthreads();

    uint2 rec[8];
#pragma unroll
    for (int j = 0; j < 8; ++j) {
        const int e = base + j * 256 + tid;
        if (e < NEDGE) {
            const int t = tidx[e];
            const float w = esgn[e] * enorm[e];
            rec[j].x = ((unsigned)sidx[e] << 16) | (unsigned)f2bf(w);
            rec[j].y = (unsigned)t;
            atomicAdd(&lcnt[wv][t >> 10], 1);
        }
    }
    __syncthreads();

    if (tid < 64) {
        int c0 = 0, c1 = 0, c2 = 0, c3 = 0, tot = 0;
        if (lane < NCB) {
            c0 = lcnt[0][lane]; c1 = lcnt[1][lane];
            c2 = lcnt[2][lane]; c3 = lcnt[3][lane];
            tot = c0 + c1 + c2 + c3;
        }
        const int inc = wave_incl_scan(tot, lane);
        const int ex = inc - tot;
        if (lane < NCB) {
            loffs[lane]    = ex;
            lbase[0][lane] = ex;
            lbase[1][lane] = ex + c0;
            lbase[2][lane] = ex + c0 + c1;
            lbase[3][lane] = ex + c0 + c1 + c2;
            grun[lane] = atomicAdd(&ccursor[lane], tot);
        }
    }
    __syncthreads();

#pragma unroll
    for (int j = 0; j < 8; ++j) {
        const int e = base + j * 256 + tid;
        if (e < NEDGE) {
            const int cb = (int)(rec[j].y >> 10);
            const int pos = atomicAdd(&lbase[wv][cb], 1);
            lrec[pos] = rec[j];
        }
    }
    __syncthreads();

    for (int i = tid; i < n; i += 256) {
        const uint2 r = lrec[i];
        const int cb = (int)(r.y >> 10);
        coarse8[grun[cb] + (i - loffs[cb])] = r;
    }
}

// ---------------------------------------------------------------------------
// hist: 4 sub-blocks per bin; len derived from ccursor. Each histograms
// its quarter into LDS, plain-stores its private 4KB slice.
// ---------------------------------------------------------------------------
__global__ __launch_bounds__(1024) void hist_kernel(
    const uint2* __restrict__ coarse8, const int* __restrict__ ccursor,
    int* __restrict__ hcnt)
{
    __shared__ int cnt[1024];
    const int tid = threadIdx.x;
    const int bin = blockIdx.x >> 2, s = blockIdx.x & 3;
    const int bs = bin * BSTRIDE;
    const int len = ccursor[bin] - bs;
    const int qs = bs + ((len * s) >> 2);
    const int qe = bs + ((len * (s + 1)) >> 2);
    cnt[tid] = 0;
    __syncthreads();
    for (int i = qs + tid; i < qe; i += 1024)
        atomicAdd(&cnt[coarse8[i].y & 1023], 1);
    __syncthreads();
    hcnt[blockIdx.x * 1024 + tid] = cnt[tid];
}

// ---------------------------------------------------------------------------
// scatter_fine: wave 0 recomputes the 49-bin packed prefix from ccursor,
// then bin-wide scan from the 4 hcnt slices, seeds LDS cursors at
// offs[v] + prefix(earlier sub-blocks), ranks + scatters its quarter.
// Sub-range formula identical to hist_kernel -> exact partition.
// ---------------------------------------------------------------------------
__global__ __launch_bounds__(1024) void scatter_fine_kernel(
    const uint2* __restrict__ coarse8, const int* __restrict__ ccursor,
    const int* __restrict__ hcnt, int* __restrict__ offs,
    unsigned int* __restrict__ pairs)
{
    __shared__ int cur[1024];
    __shared__ int wsum[16];
    __shared__ int sh_s0;
    const int tid = threadIdx.x, lane = tid & 63, wv = tid >> 6;
    const int bin = blockIdx.x >> 2, s = blockIdx.x & 3;
    const int bs = bin * BSTRIDE;

    if (tid < 64) {
        const int lenl = (tid < NCB) ? (ccursor[tid] - tid * BSTRIDE) : 0;
        const int incc = wave_incl_scan(lenl, tid);
        if (tid == bin) sh_s0 = incc - lenl;   // packed exclusive prefix
    }

    const int len = ccursor[bin] - bs;
    const int qs = bs + ((len * s) >> 2);
    const int qe = bs + ((len * (s + 1)) >> 2);

    const int c0 = hcnt[(bin * 4 + 0) * 1024 + tid];
    const int c1 = hcnt[(bin * 4 + 1) * 1024 + tid];
    const int c2 = hcnt[(bin * 4 + 2) * 1024 + tid];
    const int c3 = hcnt[(bin * 4 + 3) * 1024 + tid];
    const int tot = c0 + c1 + c2 + c3;
    const int pre = (s > 0 ? c0 : 0) + (s > 1 ? c1 : 0) + (s > 2 ? c2 : 0);

    const int inc = wave_incl_scan(tot, lane);
    if (lane == 63) wsum[wv] = inc;
    __syncthreads();
    if (tid == 0) {
        int run = 0;
        for (int i = 0; i < 16; ++i) { const int t = wsum[i]; wsum[i] = run; run += t; }
    }
    __syncthreads();
    const int ex = sh_s0 + wsum[wv] + inc - tot;   // global offs for vertex gv
    const int gv = (bin << 10) + tid;
    if (s == 0 && gv < VNUM) offs[gv] = ex;
    cur[tid] = ex + pre;
    __syncthreads();

    for (int i = qs + tid; i < qe; i += 1024) {
        const uint2 r = coarse8[i];
        const int pos = atomicAdd(&cur[r.y & 1023], 1);
        pairs[pos] = r.x;
    }
}

// ---------------------------------------------------------------------------
// aggregate: one wave per vertex, lane covers cols (2l, 2l+1). 256 B
// coalesced bf16-row gathers, unroll-12, CACHED pairs loads (R8-proven) +
// nontemporal PACKED-BF16 store (WRITE 25->12.5MB). Same rounding point as
// gemm's old pack -> bit-identical output.
// ---------------------------------------------------------------------------
__global__ __launch_bounds__(256) void aggregate_kernel(
    const int* __restrict__ offs, const unsigned int* __restrict__ pairs,
    const unsigned int* __restrict__ vrepr16, unsigned int* __restrict__ accu)
{
    const int v = blockIdx.x * 4 + (threadIdx.x >> 6);
    const int l = threadIdx.x & 63;
    int i = offs[v];
    const int end = offs[v + 1];

    float a0 = 0.0f, a1 = 0.0f;
    for (; i + 12 <= end; i += 12) {
        unsigned p[12], r[12];
#pragma unroll
        for (int j = 0; j < 12; ++j) p[j] = pairs[i + j];
#pragma unroll
        for (int j = 0; j < 12; ++j) r[j] = vrepr16[(size_t)(p[j] >> 16) * 64 + l];
#pragma unroll
        for (int j = 0; j < 12; ++j) {
            const float w = bf16_lo(p[j]);
            a0 = fmaf(bf16_lo(r[j]), w, a0);
            a1 = fmaf(bf16_hi(r[j]), w, a1);
        }
    }
    for (; i + 4 <= end; i += 4) {
        unsigned p[4], r[4];
#pragma unroll
        for (int j = 0; j < 4; ++j) p[j] = pairs[i + j];
#pragma unroll
        for (int j = 0; j < 4; ++j) r[j] = vrepr16[(size_t)(p[j] >> 16) * 64 + l];
#pragma unroll
        for (int j = 0; j < 4; ++j) {
            const float w = bf16_lo(p[j]);
            a0 = fmaf(bf16_lo(r[j]), w, a0);
            a1 = fmaf(bf16_hi(r[j]), w, a1);
        }
    }
    for (; i < end; ++i) {
        const unsigned p = pairs[i];
        const unsigned r = vrepr16[(size_t)(p >> 16) * 64 + l];
        const float w = bf16_lo(p);
        a0 = fmaf(bf16_lo(r), w, a0); a1 = fmaf(bf16_hi(r), w, a1);
    }
    const unsigned pk = (unsigned)f2bf(a0) | ((unsigned)f2bf(a1) << 16);
    __builtin_nontemporal_store(pk, accu + (size_t)v * 128 + l);
}

// ---------------------------------------------------------------------------
// gemm via MFMA 16x16x32 bf16. A-tile read pre-packed bf16: 256 B/row,
// no f32->bf16 pack phase. In-place safe: block reads exactly the acc16
// region of the rows it overwrites.
// ---------------------------------------------------------------------------
__global__ __launch_bounds__(256) void gemm_mfma_kernel(
    const unsigned int* accu, const unsigned int* __restrict__ bfrag,
    const float* __restrict__ loc_b, const float* __restrict__ std_b,
    float* out)
{
    __shared__ unsigned short tile[16][136];   // bf16, padded
    const int t = threadIdx.x;
    const int row0 = blockIdx.x * 16;
    const int l = t & 63, w = t >> 6;

    short8 bfr[4][4];
#pragma unroll
    for (int ct = 0; ct < 4; ++ct)
#pragma unroll
        for (int ks = 0; ks < 4; ++ks)
            bfr[ct][ks] = *reinterpret_cast<const short8*>(
                bfrag + ((((w * 4 + ct) * 4 + ks) * 64 + l) << 2));

    {
        const uint4 av = *reinterpret_cast<const uint4*>(
            accu + (size_t)(row0 + (t >> 4)) * 128 + (t & 15) * 4);
        *reinterpret_cast<uint4*>(&tile[t >> 4][(t & 15) * 8]) = av;
    }
    __syncthreads();

    const int m = l & 15, q = l >> 4;
    v4f accv[4];
#pragma unroll
    for (int ct = 0; ct < 4; ++ct) accv[ct] = (v4f){0.0f, 0.0f, 0.0f, 0.0f};

#pragma unroll
    for (int ks = 0; ks < 4; ++ks) {
        const short8 a = *reinterpret_cast<const short8*>(&tile[m][ks * 32 + q * 8]);
#pragma unroll
        for (int ct = 0; ct < 4; ++ct)
            accv[ct] = __builtin_amdgcn_mfma_f32_16x16x32_bf16(
                a, bfr[ct][ks], accv[ct], 0, 0, 0);
    }

#pragma unroll
    for (int ct = 0; ct < 4; ++ct) {
        const int colg = (w * 4 + ct) * 16 + m;
        const int h = colg >> 7, c = colg & 127;
        const float bias = (h ? std_b : loc_b)[c];
        float* dst = out + (h ? (size_t)VNUM * OUTF : (size_t)0);
#pragma unroll
        for (int reg = 0; reg < 4; ++reg) {
            const int row = row0 + q * 4 + reg;
            float x = accv[ct][reg] + bias;
            if (h) x = fmaxf(x, 0.0f) + log1pf(expf(-fabsf(x))) + EPSF;
            dst[(size_t)row * OUTF + c] = x;
        }
    }
}

// Fallback gemm (no workspace): f32 vector path, unpacks bf16 acc.
__global__ __launch_bounds__(256) void gemm_fallback_kernel(
    const unsigned int* accu,
    const float* __restrict__ loc_w, const float* __restrict__ loc_b,
    const float* __restrict__ std_w, const float* __restrict__ std_b,
    float* out)
{
    __shared__ float tile[16][OUTF];
    const int t = threadIdx.x;
    const int row0 = blockIdx.x * 16;
    {
        const uint4 av = *reinterpret_cast<const uint4*>(
            accu + (size_t)(row0 + (t >> 4)) * 128 + (t & 15) * 4);
        float* dst = &tile[t >> 4][(t & 15) * 8];
        dst[0] = bf16_lo(av.x); dst[1] = bf16_hi(av.x);
        dst[2] = bf16_lo(av.y); dst[3] = bf16_hi(av.y);
        dst[4] = bf16_lo(av.z); dst[5] = bf16_hi(av.z);
        dst[6] = bf16_lo(av.w); dst[7] = bf16_hi(av.w);
    }
    __syncthreads();
    const int is_std = t >> 7;
    const int c = t & 127;
    const float* w = (is_std ? std_w : loc_w) + (size_t)c * OUTF;
    const float bias = is_std ? std_b[c] : loc_b[c];
    float accv[16];
#pragma unroll
    for (int r = 0; r < 16; ++r) accv[r] = 0.0f;
    for (int k = 0; k < OUTF; k += 4) {
        const float4 wv = *reinterpret_cast<const float4*>(w + k);
#pragma unroll
        for (int r = 0; r < 16; ++r) {
            const float4 pv = *reinterpret_cast<const float4*>(&tile[r][k]);
            float a = accv[r];
            a = fmaf(pv.x, wv.x, a); a = fmaf(pv.y, wv.y, a);
            a = fmaf(pv.z, wv.z, a); a = fmaf(pv.w, wv.w, a);
            accv[r] = a;
        }
    }
    float* dst_base = out + (is_std ? (size_t)VNUM * OUTF : (size_t)0);
#pragma unroll
    for (int r = 0; r < 16; ++r) {
        const float x = accv[r] + bias;
        dst_base[(size_t)(row0 + r) * OUTF + c] =
            is_std ? (fmaxf(x, 0.0f) + log1pf(expf(-fabsf(x))) + EPSF) : x;
    }
}

extern "C" void kernel_launch(void* const* d_in, const int* in_sizes, int n_in,
                              void* d_out, int out_size, void* d_ws, size_t ws_size,
                              hipStream_t stream) {
    const int*   sidx  = (const int*)  d_in[0];
    const int*   tidx  = (const int*)  d_in[1];
    const float* enorm = (const float*)d_in[2];
    const float* esgn  = (const float*)d_in[3];
    const float* vrepr = (const float*)d_in[4];
    const float* loc_w = (const float*)d_in[5];
    const float* loc_b = (const float*)d_in[6];
    const float* std_w = (const float*)d_in[7];
    const float* std_b = (const float*)d_in[8];

    float* out = (float*)d_out;

    // coarse8: 49 fixed-stride segments (49*36864*8B = 14.45 MB) in the loc
    // half of out (25.6 MB); dead after scatter_fine. Then the loc half holds
    // acc16 (packed bf16, identity-strided: row v -> uints [v*128, v*128+64)).
    uint2* coarse8 = (uint2*)out;
    unsigned int* accu = (unsigned int*)out;

    // std-half scratch layout (~5.05M of 6.4M words):
    //   pairs 1.6M | vrepr16 3.2M | offs 50001 | ccursor 49 | hcnt 196*1024
    unsigned int* sbase   = (unsigned int*)(out + (size_t)VNUM * OUTF);
    unsigned int* pairs   = sbase;
    unsigned int* vrepr16 = sbase + NEDGE;
    int* offs    = (int*)(sbase + NEDGE + (size_t)VNUM * 64);
    int* ccursor = offs + VNUM + 1;
    int* hcnt    = ccursor + NCB;

    const bool use_ws = ws_size >= 16384 * sizeof(unsigned int);  // 64 KB
    unsigned int* bfrag = use_ws ? (unsigned int*)d_ws : nullptr;

    const int prep_blocks = CONV_BLOCKS + 1 + (use_ws ? BFRAG_BLOCKS : 0);
    prep_kernel        <<<prep_blocks, 256, 0, stream>>>(vrepr, vrepr16, ccursor,
                                                         offs, loc_w, std_w, bfrag);
    coarse_kernel      <<<COARSE_BLOCKS, 256, 0, stream>>>(sidx, tidx, enorm, esgn,
                                                           ccursor, coarse8);
    hist_kernel        <<<FINE_BLOCKS, 1024, 0, stream>>>(coarse8, ccursor, hcnt);
    scatter_fine_kernel<<<FINE_BLOCKS, 1024, 0, stream>>>(coarse8, ccursor, hcnt,
                                                          offs, pairs);
    aggregate_kernel   <<<VNUM / 4, 256, 0, stream>>>(offs, pairs, vrepr16, accu);

    if (use_ws) {
        gemm_mfma_kernel<<<VNUM / 16, 256, 0, stream>>>(accu, bfrag, loc_b, std_b, out);
    } else {
        gemm_fallback_kernel<<<VNUM / 16, 256, 0, stream>>>(accu, loc_w, loc_b,
                                                            std_w, std_b, out);
    }
}